// Round 5
// baseline (1472.257 us; speedup 1.0000x reference)
//
#include <hip/hip_runtime.h>

// LSTMNet: B=1024, T=2048, H=64, NC=10, input_size=1.
// MFMA (16x16x32 bf16) formulation with split-bf16 (hi+lo) fp32 emulation.
//   grid = 64 blocks x 256 thr (4 waves). Block owns 16 batch rows (M=16).
//   Wave w owns units [16w,16w+16); computes ALL 4 gates for those units as
//   4 N-tiles -> i,f,g,o for (row,unit) land in the same lane's accs ->
//   in-register LSTM update, c[4] persistent VGPRs, ONE barrier/step.
//   Weights: bf16 hi/lo B-fragments (guide-verified layout B[n=lane&15]
//   [k=quad*8+j]), held in 64 VGPRs (read once from LDS staging).
//   h: split hi/lo bf16, written by the updater directly in A-fragment slot
//   order (lane-contiguous ds_read_b128 next step). Double-buffered.
// R1-R4 lesson: launch_bounds' 2nd arg only sets the waves/EU MIN; the
// scheduler targets the range max (8/EU) and spills big arrays to scratch.
// Fix: amdgpu_waves_per_eu(1,1) with NO __launch_bounds__ (nothing overrides).

#define T_STEPS 2048
#define HID 64
#define NCLS 10

typedef short bf16x8 __attribute__((ext_vector_type(8)));
typedef float f32x4 __attribute__((ext_vector_type(4)));

__device__ __forceinline__ float sigm(float x) {
    float e = __builtin_amdgcn_exp2f(-1.4426950408889634f * x);
    return __builtin_amdgcn_rcpf(1.0f + e);
}
__device__ __forceinline__ float tanh_f(float x) {
    float e = __builtin_amdgcn_exp2f(-2.8853900817779268f * x);
    return fmaf(2.0f, __builtin_amdgcn_rcpf(1.0f + e), -1.0f);
}
__device__ __forceinline__ unsigned short f2bf(float f) {  // RNE f32->bf16
    unsigned u = __builtin_bit_cast(unsigned, f);
    u = u + 0x7FFFu + ((u >> 16) & 1u);
    return (unsigned short)(u >> 16);
}
__device__ __forceinline__ float bf2f(unsigned short s) {
    return __builtin_bit_cast(float, ((unsigned)s) << 16);
}

__global__ __attribute__((amdgpu_flat_work_group_size(256, 256),
                          amdgpu_waves_per_eu(1, 1)))
void lstm_mfma_kernel(
    const float* __restrict__ x,      // [B, 1, T]
    const float* __restrict__ W_ih,   // [256, 1]
    const float* __restrict__ W_hh,   // [256, 64]
    const float* __restrict__ b_ih,   // [256]
    const float* __restrict__ b_hh,   // [256]
    const float* __restrict__ fc1_w,  // [64, 64]
    const float* __restrict__ fc1_b,  // [64]
    const float* __restrict__ fc2_w,  // [10, 64]
    const float* __restrict__ fc2_b,  // [10]
    float* __restrict__ out)          // [B, 10]
{
    const int tid  = threadIdx.x;
    const int lane = tid & 63;
    const int w    = tid >> 6;        // wave id = unit group
    const int quad = lane >> 4;
    const int col  = lane & 15;
    const int row0 = blockIdx.x * 16; // batch rows [row0, row0+16)

    // LDS: W fragments (staging), A-fragment double buffer, epilogue scratch.
    __shared__ short whi[32 * 512];       // 32 frags x 512 bf16 = 32 KB
    __shared__ short wlo[32 * 512];       // 32 KB
    __shared__ short abuf[2][2048];       // [buf]: hi[0:1024) lo[1024:2048), 4 KB ea
    __shared__ float hf[16][HID + 1];
    __shared__ float r1buf[16][HID + 1];

    // ---- setup: convert W_hh f32 -> bf16 hi/lo fragments in LDS ----
    // frag id fid = ((w_*4 + g)*2 + kt); slot = (q*16 + n)*8 + j  (lane-major)
    for (int idx = tid; idx < 256 * 64; idx += 256) {
        int r_ = idx >> 6;            // gate-major row 0..255
        int k  = idx & 63;
        float f = W_hh[r_ * 64 + k];
        unsigned short hi = f2bf(f);
        unsigned short lo = f2bf(f - bf2f(hi));
        int g = r_ >> 6, u = r_ & 63;
        int w_ = u >> 4, n = u & 15;
        int kt = k >> 5, q = (k & 31) >> 3, j = k & 7;
        int off = (((w_ * 4 + g) * 2 + kt) * 64 + (q * 16 + n)) * 8 + j;
        whi[off] = (short)hi;
        wlo[off] = (short)lo;
    }
    // zero A buffer 0 (h0 = 0; bf16 zero is 0x0000)
    for (int idx = tid; idx < 2048; idx += 256) abuf[0][idx] = 0;
    __syncthreads();

    // ---- per-lane constants ----
    const int unit = w * 16 + col;
    float wih_l[4], bsum_l[4];
    #pragma unroll
    for (int g = 0; g < 4; ++g) {
        wih_l[g]  = W_ih[g * HID + unit];
        bsum_l[g] = b_ih[g * HID + unit] + b_hh[g * HID + unit];
    }

    // B fragments -> registers (64 VGPRs). Lane-contiguous 16B reads.
    bf16x8 Bhi[4][2], Blo[4][2];
    #pragma unroll
    for (int g = 0; g < 4; ++g) {
        #pragma unroll
        for (int kt = 0; kt < 2; ++kt) {
            int off = (((w * 4 + g) * 2 + kt) * 64 + lane) * 8;
            Bhi[g][kt] = *(const bf16x8*)&whi[off];
            Blo[g][kt] = *(const bf16x8*)&wlo[off];
            asm volatile("" : "+v"(Bhi[g][kt]));
            asm volatile("" : "+v"(Blo[g][kt]));
        }
    }

    // x pointers: lane handles rows m = quad*4 + r
    const float* xbase = x + (size_t)row0 * T_STEPS;
    float xcur[4], xnxt[4];
    #pragma unroll
    for (int r = 0; r < 4; ++r) xcur[r] = xbase[(quad * 4 + r) * T_STEPS];

    float c[4] = {0.f, 0.f, 0.f, 0.f};
    float hlast[4] = {0.f, 0.f, 0.f, 0.f};

    // writer's A-slot coords for (m, unit): kt=unit>>5, q=(unit&31)>>3, j=unit&7
    const int kt_w = w >> 1;
    const int q_w  = (w & 1) * 2 + (col >> 3);
    const int j_w  = col & 7;

    #pragma unroll 1
    for (int t = 0; t < T_STEPS; ++t) {
        const int cur = t & 1, nxt = cur ^ 1;

        // prefetch next x (L1-resident rows)
        const int tn = (t + 1 < T_STEPS) ? t + 1 : t;
        #pragma unroll
        for (int r = 0; r < 4; ++r)
            xnxt[r] = xbase[(quad * 4 + r) * T_STEPS + tn];

        // read A fragments (lane-contiguous b128, conflict-free)
        bf16x8 Ahi[2], Alo[2];
        #pragma unroll
        for (int kt = 0; kt < 2; ++kt) {
            Ahi[kt] = *(const bf16x8*)&abuf[cur][(kt * 64 + lane) * 8];
            Alo[kt] = *(const bf16x8*)&abuf[cur][1024 + (kt * 64 + lane) * 8];
        }

        // acc init: bias + x*wih (C/D layout: reg r -> row m = quad*4+r)
        f32x4 acc[4];
        #pragma unroll
        for (int g = 0; g < 4; ++g) {
            #pragma unroll
            for (int r = 0; r < 4; ++r)
                acc[g][r] = fmaf(xcur[r], wih_l[g], bsum_l[g]);
        }

        // 3-pass split-precision MFMA: Whi*hhi + Whi*hlo + Wlo*hhi
        #pragma unroll
        for (int g = 0; g < 4; ++g) {
            #pragma unroll
            for (int kt = 0; kt < 2; ++kt) {
                acc[g] = __builtin_amdgcn_mfma_f32_16x16x32_bf16(Ahi[kt], Bhi[g][kt], acc[g], 0, 0, 0);
                acc[g] = __builtin_amdgcn_mfma_f32_16x16x32_bf16(Alo[kt], Bhi[g][kt], acc[g], 0, 0, 0);
                acc[g] = __builtin_amdgcn_mfma_f32_16x16x32_bf16(Ahi[kt], Blo[g][kt], acc[g], 0, 0, 0);
            }
        }

        // in-register LSTM update; write h (hi/lo bf16) into next A buffer
        #pragma unroll
        for (int r = 0; r < 4; ++r) {
            float ig = sigm(acc[0][r]);
            float fg = sigm(acc[1][r]);
            float gg = tanh_f(acc[2][r]);
            float og = sigm(acc[3][r]);
            c[r] = fmaf(fg, c[r], ig * gg);
            float h = og * tanh_f(c[r]);
            hlast[r] = h;
            unsigned short hh = f2bf(h);
            unsigned short hl = f2bf(h - bf2f(hh));
            int m = quad * 4 + r;
            int slot = (kt_w * 64 + (q_w * 16 + m)) * 8 + j_w;
            abuf[nxt][slot]        = (short)hh;
            abuf[nxt][1024 + slot] = (short)hl;
        }

        #pragma unroll
        for (int r = 0; r < 4; ++r) xcur[r] = xnxt[r];

        __syncthreads();  // next A buffer complete for all waves
    }

    // ---- epilogue: fc1 (relu) + fc2, once per block ----
    #pragma unroll
    for (int r = 0; r < 4; ++r) hf[quad * 4 + r][unit] = hlast[r];
    __syncthreads();

    {
        int m_ = tid & 15, ug = tid >> 4;  // thread: row m_, units ug*4..+3
        #pragma unroll
        for (int uu = 0; uu < 4; ++uu) {
            int u = ug * 4 + uu;
            float s = fc1_b[u];
            const float4* wrow = (const float4*)(fc1_w + u * HID);
            #pragma unroll
            for (int j4 = 0; j4 < HID / 4; ++j4) {
                float4 wv = wrow[j4];
                s = fmaf(hf[m_][j4 * 4 + 0], wv.x, s);
                s = fmaf(hf[m_][j4 * 4 + 1], wv.y, s);
                s = fmaf(hf[m_][j4 * 4 + 2], wv.z, s);
                s = fmaf(hf[m_][j4 * 4 + 3], wv.w, s);
            }
            r1buf[m_][u] = fmaxf(s, 0.0f);
        }
    }
    __syncthreads();

    if (tid < 16 * NCLS) {
        int m = tid / NCLS, cls = tid % NCLS;
        float s = fc2_b[cls];
        const float* w2 = fc2_w + cls * HID;
        #pragma unroll
        for (int j = 0; j < HID; ++j) s = fmaf(r1buf[m][j], w2[j], s);
        out[(size_t)(row0 + m) * NCLS + cls] = s;
    }
}

extern "C" void kernel_launch(void* const* d_in, const int* in_sizes, int n_in,
                              void* d_out, int out_size, void* d_ws, size_t ws_size,
                              hipStream_t stream) {
    const float* x     = (const float*)d_in[0];
    const float* W_ih  = (const float*)d_in[1];
    const float* W_hh  = (const float*)d_in[2];
    const float* b_ih  = (const float*)d_in[3];
    const float* b_hh  = (const float*)d_in[4];
    const float* fc1_w = (const float*)d_in[5];
    const float* fc1_b = (const float*)d_in[6];
    const float* fc2_w = (const float*)d_in[7];
    const float* fc2_b = (const float*)d_in[8];
    float* out = (float*)d_out;

    dim3 grid(64);    // 1024 rows / 16 rows per block
    dim3 block(256);  // 4 waves
    lstm_mfma_kernel<<<grid, block, 0, stream>>>(x, W_ih, W_hh, b_ih, b_hh,
                                                 fc1_w, fc1_b, fc2_w, fc2_b, out);
}

// Round 6
// 1438.658 us; speedup vs baseline: 1.0234x; 1.0234x over previous
//
#include <hip/hip_runtime.h>

// LSTMNet: B=1024, T=2048, H=64, NC=10, input_size=1.
// MFMA (16x16x32 bf16) split-bf16 (hi+lo) fp32 emulation. Structure from R5
// (verified correct, absmax 3e-5):
//   grid = 64 blocks x 256 thr (4 waves); block owns 16 batch rows.
//   Wave w owns units [16w,16w+16), computes all 4 gates -> in-register LSTM
//   update, c[4] persistent, ONE barrier/step.
// R6 changes (chain-shortening; wall time == per-step serial chain x 2048):
//   1. x staged via LDS in 128-step chunks -> NO global loads in steady loop
//      -> __syncthreads no longer drains vmcnt(0) every step (R5's big stall).
//   2. x*W_ih applied AFTER the MFMAs (acc init = bias only) -> x ds_read is
//      off the critical path.
//   3. kt-split accumulators (accA: kt0 from bias, accB: kt1 from 0, merged
//      once) -> MFMA dependency depth 6 -> 3.
// Known-deferred: 8-way bank conflict on b16 h-writes (~4% of runtime).

#define T_STEPS 2048
#define HID 64
#define NCLS 10
#define XCH 128   // x chunk length (steps)

typedef short bf16x8 __attribute__((ext_vector_type(8)));
typedef float f32x4 __attribute__((ext_vector_type(4)));

__device__ __forceinline__ float sigm(float x) {
    float e = __builtin_amdgcn_exp2f(-1.4426950408889634f * x);
    return __builtin_amdgcn_rcpf(1.0f + e);
}
__device__ __forceinline__ float tanh_f(float x) {
    float e = __builtin_amdgcn_exp2f(-2.8853900817779268f * x);
    return fmaf(2.0f, __builtin_amdgcn_rcpf(1.0f + e), -1.0f);
}
__device__ __forceinline__ unsigned short f2bf(float f) {  // RNE f32->bf16
    unsigned u = __builtin_bit_cast(unsigned, f);
    u = u + 0x7FFFu + ((u >> 16) & 1u);
    return (unsigned short)(u >> 16);
}
__device__ __forceinline__ float bf2f(unsigned short s) {
    return __builtin_bit_cast(float, ((unsigned)s) << 16);
}

__global__ __attribute__((amdgpu_flat_work_group_size(256, 256),
                          amdgpu_waves_per_eu(1, 1)))
void lstm_mfma_kernel(
    const float* __restrict__ x,      // [B, 1, T]
    const float* __restrict__ W_ih,   // [256, 1]
    const float* __restrict__ W_hh,   // [256, 64]
    const float* __restrict__ b_ih,   // [256]
    const float* __restrict__ b_hh,   // [256]
    const float* __restrict__ fc1_w,  // [64, 64]
    const float* __restrict__ fc1_b,  // [64]
    const float* __restrict__ fc2_w,  // [10, 64]
    const float* __restrict__ fc2_b,  // [10]
    float* __restrict__ out)          // [B, 10]
{
    const int tid  = threadIdx.x;
    const int lane = tid & 63;
    const int w    = tid >> 6;        // wave id = unit group
    const int quad = lane >> 4;
    const int col  = lane & 15;
    const int row0 = blockIdx.x * 16; // batch rows [row0, row0+16)

    __shared__ short whi[32 * 512];        // 32 KB: W_hh hi fragments
    __shared__ short wlo[32 * 512];        // 32 KB: W_hh lo fragments
    __shared__ short abuf[2][2048];        // A frags double buffer (hi|lo)
    __shared__ __align__(16) float xlds[XCH][16];  // 8 KB x chunk [t_local][row]
    __shared__ float hf[16][HID + 1];
    __shared__ float r1buf[16][HID + 1];

    // ---- setup: convert W_hh f32 -> bf16 hi/lo fragments in LDS ----
    for (int idx = tid; idx < 256 * 64; idx += 256) {
        int r_ = idx >> 6;            // gate-major row 0..255
        int k  = idx & 63;
        float f = W_hh[r_ * 64 + k];
        unsigned short hi = f2bf(f);
        unsigned short lo = f2bf(f - bf2f(hi));
        int g = r_ >> 6, u = r_ & 63;
        int w_ = u >> 4, n = u & 15;
        int kt = k >> 5, q = (k & 31) >> 3, j = k & 7;
        int off = (((w_ * 4 + g) * 2 + kt) * 64 + (q * 16 + n)) * 8 + j;
        whi[off] = (short)hi;
        wlo[off] = (short)lo;
    }
    for (int idx = tid; idx < 2048; idx += 256) abuf[0][idx] = 0;  // h0 = 0
    __syncthreads();

    // ---- per-lane constants ----
    const int unit = w * 16 + col;
    float wih_l[4], bsum_l[4];
    #pragma unroll
    for (int g = 0; g < 4; ++g) {
        wih_l[g]  = W_ih[g * HID + unit];
        bsum_l[g] = b_ih[g * HID + unit] + b_hh[g * HID + unit];
    }

    // B fragments -> registers (64 VGPRs), lane-contiguous 16B reads.
    bf16x8 Bhi[4][2], Blo[4][2];
    #pragma unroll
    for (int g = 0; g < 4; ++g) {
        #pragma unroll
        for (int kt = 0; kt < 2; ++kt) {
            int off = (((w * 4 + g) * 2 + kt) * 64 + lane) * 8;
            Bhi[g][kt] = *(const bf16x8*)&whi[off];
            Blo[g][kt] = *(const bf16x8*)&wlo[off];
            asm volatile("" : "+v"(Bhi[g][kt]));
            asm volatile("" : "+v"(Blo[g][kt]));
        }
    }

    const float* xbase = x + (size_t)row0 * T_STEPS;
    // x chunk loader coords: thread -> (row, 8 consecutive t)
    const int xl_row = tid >> 4;
    const int xl_tb  = (tid & 15) * 8;

    float c[4] = {0.f, 0.f, 0.f, 0.f};
    float hlast[4] = {0.f, 0.f, 0.f, 0.f};

    // writer's A-slot coords for (m, unit): kt=unit>>5, q=(unit&31)>>3, j=unit&7
    const int kt_w = w >> 1;
    const int q_w  = (w & 1) * 2 + (col >> 3);
    const int j_w  = col & 7;

    #pragma unroll 1
    for (int t = 0; t < T_STEPS; ++t) {
        const int cur = t & 1, nxt = cur ^ 1;
        const int tl = t & (XCH - 1);

        if (tl == 0) {
            // refill x chunk: prior end-of-step barrier guarantees the old
            // chunk is fully consumed. One coalesced load per thread pair of
            // float4s; vmcnt drained before the extra barrier (once/128 steps).
            const float* src = xbase + (size_t)xl_row * T_STEPS + t + xl_tb;
            float4 v0 = *(const float4*)(src);
            float4 v1 = *(const float4*)(src + 4);
            xlds[xl_tb + 0][xl_row] = v0.x;
            xlds[xl_tb + 1][xl_row] = v0.y;
            xlds[xl_tb + 2][xl_row] = v0.z;
            xlds[xl_tb + 3][xl_row] = v0.w;
            xlds[xl_tb + 4][xl_row] = v1.x;
            xlds[xl_tb + 5][xl_row] = v1.y;
            xlds[xl_tb + 6][xl_row] = v1.z;
            xlds[xl_tb + 7][xl_row] = v1.w;
            __syncthreads();
        }

        // x for this lane's 4 rows (broadcast b128; consumed post-MFMA)
        f32x4 xv = *(const f32x4*)&xlds[tl][quad * 4];

        // A fragments (lane-contiguous b128, conflict-free)
        bf16x8 Ahi[2], Alo[2];
        #pragma unroll
        for (int kt = 0; kt < 2; ++kt) {
            Ahi[kt] = *(const bf16x8*)&abuf[cur][(kt * 64 + lane) * 8];
            Alo[kt] = *(const bf16x8*)&abuf[cur][1024 + (kt * 64 + lane) * 8];
        }

        // kt-split accumulators: depth-3 MFMA chains, merged once.
        f32x4 accA[4], accB[4];
        #pragma unroll
        for (int g = 0; g < 4; ++g) {
            #pragma unroll
            for (int r = 0; r < 4; ++r) { accA[g][r] = bsum_l[g]; accB[g][r] = 0.f; }
        }
        #pragma unroll
        for (int g = 0; g < 4; ++g) {
            accA[g] = __builtin_amdgcn_mfma_f32_16x16x32_bf16(Ahi[0], Bhi[g][0], accA[g], 0, 0, 0);
            accB[g] = __builtin_amdgcn_mfma_f32_16x16x32_bf16(Ahi[1], Bhi[g][1], accB[g], 0, 0, 0);
            accA[g] = __builtin_amdgcn_mfma_f32_16x16x32_bf16(Alo[0], Bhi[g][0], accA[g], 0, 0, 0);
            accB[g] = __builtin_amdgcn_mfma_f32_16x16x32_bf16(Alo[1], Bhi[g][1], accB[g], 0, 0, 0);
            accA[g] = __builtin_amdgcn_mfma_f32_16x16x32_bf16(Ahi[0], Blo[g][0], accA[g], 0, 0, 0);
            accB[g] = __builtin_amdgcn_mfma_f32_16x16x32_bf16(Ahi[1], Blo[g][1], accB[g], 0, 0, 0);
        }
        f32x4 acc[4];
        #pragma unroll
        for (int g = 0; g < 4; ++g) acc[g] = accA[g] + accB[g];

        // in-register LSTM update (x contribution folded in here, off-chain);
        // write h (hi/lo bf16) into next A buffer.
        #pragma unroll
        for (int r = 0; r < 4; ++r) {
            float ig = sigm(fmaf(xv[r], wih_l[0], acc[0][r]));
            float fg = sigm(fmaf(xv[r], wih_l[1], acc[1][r]));
            float gg = tanh_f(fmaf(xv[r], wih_l[2], acc[2][r]));
            float og = sigm(fmaf(xv[r], wih_l[3], acc[3][r]));
            c[r] = fmaf(fg, c[r], ig * gg);
            float h = og * tanh_f(c[r]);
            hlast[r] = h;
            unsigned short hh = f2bf(h);
            unsigned short hl = f2bf(h - bf2f(hh));
            int m = quad * 4 + r;
            int slot = (kt_w * 64 + (q_w * 16 + m)) * 8 + j_w;
            abuf[nxt][slot]        = (short)hh;
            abuf[nxt][1024 + slot] = (short)hl;
        }

        __syncthreads();  // next A buffer complete for all waves
    }

    // ---- epilogue: fc1 (relu) + fc2, once per block ----
    #pragma unroll
    for (int r = 0; r < 4; ++r) hf[quad * 4 + r][unit] = hlast[r];
    __syncthreads();

    {
        int m_ = tid & 15, ug = tid >> 4;  // thread: row m_, units ug*4..+3
        #pragma unroll
        for (int uu = 0; uu < 4; ++uu) {
            int u = ug * 4 + uu;
            float s = fc1_b[u];
            const float4* wrow = (const float4*)(fc1_w + u * HID);
            #pragma unroll
            for (int j4 = 0; j4 < HID / 4; ++j4) {
                float4 wv = wrow[j4];
                s = fmaf(hf[m_][j4 * 4 + 0], wv.x, s);
                s = fmaf(hf[m_][j4 * 4 + 1], wv.y, s);
                s = fmaf(hf[m_][j4 * 4 + 2], wv.z, s);
                s = fmaf(hf[m_][j4 * 4 + 3], wv.w, s);
            }
            r1buf[m_][u] = fmaxf(s, 0.0f);
        }
    }
    __syncthreads();

    if (tid < 16 * NCLS) {
        int m = tid / NCLS, cls = tid % NCLS;
        float s = fc2_b[cls];
        const float* w2 = fc2_w + cls * HID;
        #pragma unroll
        for (int j = 0; j < HID; ++j) s = fmaf(r1buf[m][j], w2[j], s);
        out[(size_t)(row0 + m) * NCLS + cls] = s;
    }
}

extern "C" void kernel_launch(void* const* d_in, const int* in_sizes, int n_in,
                              void* d_out, int out_size, void* d_ws, size_t ws_size,
                              hipStream_t stream) {
    const float* x     = (const float*)d_in[0];
    const float* W_ih  = (const float*)d_in[1];
    const float* W_hh  = (const float*)d_in[2];
    const float* b_ih  = (const float*)d_in[3];
    const float* b_hh  = (const float*)d_in[4];
    const float* fc1_w = (const float*)d_in[5];
    const float* fc1_b = (const float*)d_in[6];
    const float* fc2_w = (const float*)d_in[7];
    const float* fc2_b = (const float*)d_in[8];
    float* out = (float*)d_out;

    dim3 grid(64);    // 1024 rows / 16 rows per block
    dim3 block(256);  // 4 waves
    lstm_mfma_kernel<<<grid, block, 0, stream>>>(x, W_ih, W_hh, b_ih, b_hh,
                                                 fc1_w, fc1_b, fc2_w, fc2_b, out);
}